// Round 3
// baseline (456.021 us; speedup 1.0000x reference)
//
#include <hip/hip_runtime.h>
#include <hip/hip_fp16.h>

// GCN VGAE encoder:
//   h  = relu((A @ x) @ W1 + b1)          [associativity: A(xW) == (Ax)W]
//   mu = (A @ h) @ Wmu + bmu ; lv = (A @ h) @ Wlv + blv
// A = D^-1/2 (Adj + I) D^-1/2, deg on dst side. dinv folded into tables:
//   xs[s]=dinv_s*x[s]; hs[i]=dinv_i*relu(...); y_i = dinv_i*(sum_e xs[src]+xs[i])
//
// R14: build pipeline collapsed 6 CSR dispatches -> 2. R13 showed build bytes
// are irrelevant (packing tmp 8B->4B + 2x build width = neutral); the ~125us
// build cost is launch serialization + per-kernel fixed cost, not traffic.
//  * scatter_direct: ONE edge pass. Global atomic sub-cursors (8 per bucket,
//    sub = bucket*8 + (tid&7); 1.6M atomics / 1568 addrs ~ 1k each -> ~5us at
//    L2 RMW rates). Monotone global cursors => writes per sub-region are
//    dense + temporally clustered (good L2 locality). cap = mean+32sigma,
//    pos<cap guard (drop-on-overflow, statistically impossible at 32sigma).
//  * bucket_build prologue: CSR base = block-wide reduce of the 1568 final
//    cursors (replaces the whole block_sums/scan_bsums/scan_apply chain and
//    bucket_count's full edge pass).
//  * memset(cursors) via hipMemsetAsync (graph-capturable stream op).
// Aggs + cast_scale: exact R11 config (proven 56.6us each; gather plateau).

#define BKT_SHIFT 9
#define BKT_NODES 512

typedef __attribute__((ext_vector_type(8))) _Float16 half8;
typedef __attribute__((ext_vector_type(4))) float float4v;
typedef __attribute__((ext_vector_type(4))) unsigned uint4v;

__device__ __forceinline__ int imin(int a, int b) { return a < b ? a : b; }
__device__ __forceinline__ int imax(int a, int b) { return a > b ? a : b; }
__device__ __forceinline__ unsigned h2u(__half2 v) {
  union { __half2 h; unsigned u; } c; c.h = v; return c.u;
}
__device__ __forceinline__ __half2 u2h(unsigned x) {
  union { unsigned u; __half2 h; } c; c.u = x; return c.h;
}

// ---------------- single-pass bucketed scatter (global atomic cursors) -----
// tmp entry packed: (src << 9) | (dst & 511)  [src < 2^17 for N=100k].
// Sub-region r of bucket b occupies tmp[(b*8+r)*cap ... +cap).
__global__ __launch_bounds__(256) void scatter_direct(const int* __restrict__ src,
                                                      const int* __restrict__ dst,
                                                      int* __restrict__ cursors,
                                                      int* __restrict__ tmp,
                                                      int E, int cap) {
  const int T = (E + 3) >> 2;
  const int i4 = blockIdx.x * 256 + threadIdx.x;
  if (i4 >= T) return;
  const int lane8 = threadIdx.x & 7;
  const int e = i4 * 4;
  if (e + 3 < E) {
    const int4 s4 = *(const int4*)(src + e);
    const int4 d4 = *(const int4*)(dst + e);
    int sub, pos;
    sub = (d4.x >> BKT_SHIFT) * 8 + lane8;
    pos = atomicAdd(&cursors[sub], 1);
    if (pos < cap) tmp[(size_t)sub * cap + pos] = (s4.x << 9) | (d4.x & 511);
    sub = (d4.y >> BKT_SHIFT) * 8 + lane8;
    pos = atomicAdd(&cursors[sub], 1);
    if (pos < cap) tmp[(size_t)sub * cap + pos] = (s4.y << 9) | (d4.y & 511);
    sub = (d4.z >> BKT_SHIFT) * 8 + lane8;
    pos = atomicAdd(&cursors[sub], 1);
    if (pos < cap) tmp[(size_t)sub * cap + pos] = (s4.z << 9) | (d4.z & 511);
    sub = (d4.w >> BKT_SHIFT) * 8 + lane8;
    pos = atomicAdd(&cursors[sub], 1);
    if (pos < cap) tmp[(size_t)sub * cap + pos] = (s4.w << 9) | (d4.w & 511);
  } else {
    for (int k = e; k < E; ++k) {
      const int d = dst[k];
      const int sub = (d >> BKT_SHIFT) * 8 + lane8;
      const int pos = atomicAdd(&cursors[sub], 1);
      if (pos < cap) tmp[(size_t)sub * cap + pos] = (src[k] << 9) | (d & 511);
    }
  }
}

// B: one block per bucket (1024 threads). Prologue: CSR base = reduce of all
// sub-cursor counts below this bucket. Then LDS node histogram over the 8
// sub-regions -> 512-wide LDS scan -> row_ptr/dinv (coalesced) -> LDS-cursor
// fill of pairs inside the bucket's CSR window.
__global__ __launch_bounds__(1024) void bucket_build(const int* __restrict__ tmp,
                                                     const int* __restrict__ subcnt,
                                                     int* __restrict__ row_ptr,
                                                     float* __restrict__ dinv,
                                                     int* __restrict__ pairs,
                                                     int n, int nbk, int cap, int E) {
  __shared__ int hist[BKT_NODES];
  __shared__ int scn[BKT_NODES];
  __shared__ int red[1024];
  const int b = blockIdx.x;
  const int t = threadIdx.x;
  const int node0 = b << BKT_SHIFT;
  // CSR base of bucket b = sum of subcnt[0 .. 8b)
  int a = 0;
  for (int i = t; i < 8 * b; i += 1024) a += subcnt[i];
  red[t] = a;
  if (t < BKT_NODES) hist[t] = 0;
  __syncthreads();
  for (int off = 512; off > 0; off >>= 1) {
    if (t < off) red[t] += red[t + off];
    __syncthreads();
  }
  const int s = red[0];
  // node histogram over this bucket's 8 sub-regions
  for (int r = 0; r < 8; ++r) {
    const int cr = imin(subcnt[8 * b + r], cap);
    const int* tp = tmp + (size_t)(8 * b + r) * cap;
    for (int k = t; k < cr; k += 1024) atomicAdd(&hist[tp[k] & 511], 1);
  }
  __syncthreads();
  int v = 0;
  if (t < BKT_NODES) {
    v = hist[t];
    scn[t] = v;
  }
  __syncthreads();
  for (int off = 1; off < BKT_NODES; off <<= 1) {
    int u = 0;
    if (t < BKT_NODES && t >= off) u = scn[t - off];
    __syncthreads();
    if (t < BKT_NODES) scn[t] += u;
    __syncthreads();
  }
  if (t < BKT_NODES) {
    const int excl = s + scn[t] - v;  // exclusive prefix = CSR start of node0+t
    const int node = node0 + t;
    if (node < n) {
      row_ptr[node] = excl;
      dinv[node] = rsqrtf(1.0f + (float)v);  // deg includes self-loop
    }
    if (b == nbk - 1 && t == 0) row_ptr[n] = E;
    hist[t] = excl;  // reuse as cursor
  }
  __syncthreads();
  for (int r = 0; r < 8; ++r) {
    const int cr = imin(subcnt[8 * b + r], cap);
    const int* tp = tmp + (size_t)(8 * b + r) * cap;
    for (int k = t; k < cr; k += 1024) {
      const int w = tp[k];
      const int pos = atomicAdd(&hist[w & 511], 1);
      pairs[pos] = w >> 9;
    }
  }
}

// ---------------- table prep ----------------
// xs[i] = dinv[i] * x[i] in fp16; zeros sentinel row `nrow` of xs and hs.
__global__ __launch_bounds__(256) void cast_scale(const float* __restrict__ x,
                                                  const float* __restrict__ dinv,
                                                  __half* __restrict__ xs,
                                                  __half* __restrict__ hs,
                                                  int n4, int nrow) {
  int i = blockIdx.x * blockDim.x + threadIdx.x;
  if (i < n4) {
    float4 v = ((const float4*)x)[i];
    float d = dinv[i >> 4];
    __half2* o = (__half2*)(xs + (size_t)i * 4);
    o[0] = __floats2half2_rn(d * v.x, d * v.y);
    o[1] = __floats2half2_rn(d * v.z, d * v.w);
  } else if (i < n4 + 32) {
    int j = i - n4;
    if (j < 16)
      ((float2*)(xs + (size_t)nrow * 64))[j] = make_float2(0.f, 0.f);
    else
      ((float2*)(hs + (size_t)nrow * 64))[j - 16] = make_float2(0.f, 0.f);
  }
}

// ---------------- aggregation + fused dense via MFMA (R8/R11 config) -------
// Wave handles 16 rows (4 groups of 4 rows interleaved). Per row: 8 edge
// slots (lane=8g+q, 16B of 8 halves/lane), packed-half2 accumulate; 4 rows'
// pairs-prefetch + gather chains run concurrently. One xor-32 fold (slots
// 8->4), self-term on g==0, di-scale, store to wave-private LDS A-tile
// ylds[row][(g&3)*64 + 8q+c] (K'=256; last 4-slot reduction rides the MFMA
// K-dim, B = W replicated over the 4 slots). 8 k-steps x 4 n-tiles of
// mfma_f32_16x16x32_f16, bias in C-init.
// A layout: A[m=lane&15][k=(lane>>4)*8+j]; C/D: col=lane&15, row=quad*4+reg.

#define YSTRIDE 264  // 256 + 8 halves pad

__global__ __launch_bounds__(256, 4) void agg_layer1(const __half* __restrict__ xs,
                                                     const int* __restrict__ pairs,
                                                     const int* __restrict__ row_ptr,
                                                     const float* __restrict__ W1,
                                                     const float* __restrict__ b1,
                                                     __half* __restrict__ hs, int n) {
  __shared__ _Float16 ylds_all[4][16 * YSTRIDE];
  __shared__ float dilds_all[4][16];
  const int wv = threadIdx.x >> 6;
  _Float16* ylds = ylds_all[wv];
  float* dilds = dilds_all[wv];
  const int lane = threadIdx.x & 63;
  const int g = lane >> 3, q = lane & 7;
  const int quad = lane >> 4, col = lane & 15;

  // B-fragments: k = s2*32 + quad*8 + jj; feature = k & 63 -> sW = s2 & 1.
  half8 bfrag[2][4];
#pragma unroll
  for (int s = 0; s < 2; ++s)
#pragma unroll
    for (int t = 0; t < 4; ++t)
#pragma unroll
      for (int jj = 0; jj < 8; ++jj)
        bfrag[s][t][jj] = (_Float16)W1[(s * 32 + quad * 8 + jj) * 64 + t * 16 + col];
  float bias[4];
#pragma unroll
  for (int t = 0; t < 4; ++t) bias[t] = b1[t * 16 + col];

  const int ntiles = (n + 15) >> 4;
  for (int tile = blockIdx.x * 4 + wv; tile < ntiles; tile += gridDim.x * 4) {
    const int row0 = tile << 4;
#pragma unroll 1
    for (int rg = 0; rg < 4; ++rg) {  // 4 rows interleaved per group
      int start[4], end[4], idx[4];
      __half2 acc[4][4];
      int maxdeg = 0;
#pragma unroll
      for (int j = 0; j < 4; ++j) {
        const int i = row0 + rg * 4 + j;
        start[j] = 0; end[j] = 0;
        if (i < n) { start[j] = row_ptr[i]; end[j] = row_ptr[i + 1]; }
        maxdeg = imax(maxdeg, end[j] - start[j]);
#pragma unroll
        for (int k = 0; k < 4; ++k) acc[j][k] = u2h(0u);
        idx[j] = (start[j] + g < end[j]) ? pairs[start[j] + g] : n;
      }
      const int iters = (maxdeg + 7) >> 3;
#pragma unroll 1
      for (int it = 0; it < iters; ++it) {
        int nidx[4];
#pragma unroll
        for (int j = 0; j < 4; ++j) {
          const int ofs2 = start[j] + (it + 1) * 8 + g;
          nidx[j] = (ofs2 < end[j]) ? pairs[ofs2] : n;
        }
#pragma unroll
        for (int j = 0; j < 4; ++j) {
          const float4 rr = *(const float4*)(xs + (size_t)idx[j] * 64 + q * 8);
          const __half2* hp = (const __half2*)&rr;
#pragma unroll
          for (int k = 0; k < 4; ++k) acc[j][k] = __hadd2(acc[j][k], hp[k]);
        }
#pragma unroll
        for (int j = 0; j < 4; ++j) idx[j] = nidx[j];
      }
#pragma unroll
      for (int j = 0; j < 4; ++j) {
        const int i = row0 + rg * 4 + j;
        // self term (once, on g==0 lanes)
        if (g == 0 && i < n) {
          const float4 sr = *(const float4*)(xs + (size_t)i * 64 + q * 8);
          const __half2* hp = (const __half2*)&sr;
#pragma unroll
          for (int k = 0; k < 4; ++k) acc[j][k] = __hadd2(acc[j][k], hp[k]);
        }
        // fold slots g and g^4 (lane xor 32)
#pragma unroll
        for (int k = 0; k < 4; ++k) {
          unsigned u = __shfl_xor(h2u(acc[j][k]), 32);
          acc[j][k] = __hadd2(acc[j][k], u2h(u));
        }
        const float di = rsqrtf((float)(1 + end[j] - start[j]));
        const __half hdi = __float2half(di);
        const __half2 di2 = __halves2half2(hdi, hdi);
        uint4v st;
        st.x = h2u(__hmul2(di2, acc[j][0]));
        st.y = h2u(__hmul2(di2, acc[j][1]));
        st.z = h2u(__hmul2(di2, acc[j][2]));
        st.w = h2u(__hmul2(di2, acc[j][3]));
        *(uint4v*)(ylds + (rg * 4 + j) * YSTRIDE + (g & 3) * 64 + q * 8) = st;
        if (lane == 0) dilds[rg * 4 + j] = di;
      }
    }
    // MFMA: D = A(16x256) * B'(256x64) + bias
    float4v acc[4];
#pragma unroll
    for (int t = 0; t < 4; ++t) acc[t] = (float4v){bias[t], bias[t], bias[t], bias[t]};
#pragma unroll
    for (int s2 = 0; s2 < 8; ++s2) {
      half8 af = *(half8*)(ylds + col * YSTRIDE + s2 * 32 + quad * 8);
      const int sW = s2 & 1;
#pragma unroll
      for (int t = 0; t < 4; ++t)
        acc[t] = __builtin_amdgcn_mfma_f32_16x16x32_f16(af, bfrag[sW][t], acc[t], 0, 0, 0);
    }
    const float4 dis = *(const float4*)(dilds + quad * 4);
    const float dd[4] = {dis.x, dis.y, dis.z, dis.w};
#pragma unroll
    for (int t = 0; t < 4; ++t)
#pragma unroll
      for (int reg = 0; reg < 4; ++reg) {
        const int row = row0 + quad * 4 + reg;
        if (row < n)
          hs[(size_t)row * 64 + t * 16 + col] =
              __float2half(dd[reg] * fmaxf(acc[t][reg], 0.f));
      }
  }
}

// Layer 2: same structure; B' = [Wmu | Wlv] (64 cols), fp32 outputs.
__global__ __launch_bounds__(256, 4) void agg_layer2(const __half* __restrict__ hsin,
                                                     const int* __restrict__ pairs,
                                                     const int* __restrict__ row_ptr,
                                                     const float* __restrict__ Wmu,
                                                     const float* __restrict__ bmu,
                                                     const float* __restrict__ Wlv,
                                                     const float* __restrict__ blv,
                                                     float* __restrict__ out_mu,
                                                     float* __restrict__ out_lv, int n) {
  __shared__ _Float16 ylds_all[4][16 * YSTRIDE];
  const int wv = threadIdx.x >> 6;
  _Float16* ylds = ylds_all[wv];
  const int lane = threadIdx.x & 63;
  const int g = lane >> 3, q = lane & 7;
  const int quad = lane >> 4, col = lane & 15;

  half8 bfrag[2][4];
#pragma unroll
  for (int s = 0; s < 2; ++s)
#pragma unroll
    for (int t = 0; t < 4; ++t) {
      const int j = t * 16 + col;
      const float* W = (j < 32) ? Wmu : Wlv;
      const int jc = j & 31;
#pragma unroll
      for (int jj = 0; jj < 8; ++jj)
        bfrag[s][t][jj] = (_Float16)W[(s * 32 + quad * 8 + jj) * 32 + jc];
    }
  float bias[4];
#pragma unroll
  for (int t = 0; t < 4; ++t) {
    const int j = t * 16 + col;
    bias[t] = (j < 32) ? bmu[j] : blv[j - 32];
  }

  const int ntiles = (n + 15) >> 4;
  for (int tile = blockIdx.x * 4 + wv; tile < ntiles; tile += gridDim.x * 4) {
    const int row0 = tile << 4;
#pragma unroll 1
    for (int rg = 0; rg < 4; ++rg) {
      int start[4], end[4], idx[4];
      __half2 acc[4][4];
      int maxdeg = 0;
#pragma unroll
      for (int j = 0; j < 4; ++j) {
        const int i = row0 + rg * 4 + j;
        start[j] = 0; end[j] = 0;
        if (i < n) { start[j] = row_ptr[i]; end[j] = row_ptr[i + 1]; }
        maxdeg = imax(maxdeg, end[j] - start[j]);
#pragma unroll
        for (int k = 0; k < 4; ++k) acc[j][k] = u2h(0u);
        idx[j] = (start[j] + g < end[j]) ? pairs[start[j] + g] : n;
      }
      const int iters = (maxdeg + 7) >> 3;
#pragma unroll 1
      for (int it = 0; it < iters; ++it) {
        int nidx[4];
#pragma unroll
        for (int j = 0; j < 4; ++j) {
          const int ofs2 = start[j] + (it + 1) * 8 + g;
          nidx[j] = (ofs2 < end[j]) ? pairs[ofs2] : n;
        }
#pragma unroll
        for (int j = 0; j < 4; ++j) {
          const float4 rr = *(const float4*)(hsin + (size_t)idx[j] * 64 + q * 8);
          const __half2* hp = (const __half2*)&rr;
#pragma unroll
          for (int k = 0; k < 4; ++k) acc[j][k] = __hadd2(acc[j][k], hp[k]);
        }
#pragma unroll
        for (int j = 0; j < 4; ++j) idx[j] = nidx[j];
      }
#pragma unroll
      for (int j = 0; j < 4; ++j) {
        const int i = row0 + rg * 4 + j;
        if (g == 0 && i < n) {
          const float4 sr = *(const float4*)(hsin + (size_t)i * 64 + q * 8);
          const __half2* hp = (const __half2*)&sr;
#pragma unroll
          for (int k = 0; k < 4; ++k) acc[j][k] = __hadd2(acc[j][k], hp[k]);
        }
#pragma unroll
        for (int k = 0; k < 4; ++k) {
          unsigned u = __shfl_xor(h2u(acc[j][k]), 32);
          acc[j][k] = __hadd2(acc[j][k], u2h(u));
        }
        const float di = rsqrtf((float)(1 + end[j] - start[j]));
        const __half hdi = __float2half(di);
        const __half2 di2 = __halves2half2(hdi, hdi);
        uint4v st;
        st.x = h2u(__hmul2(di2, acc[j][0]));
        st.y = h2u(__hmul2(di2, acc[j][1]));
        st.z = h2u(__hmul2(di2, acc[j][2]));
        st.w = h2u(__hmul2(di2, acc[j][3]));
        *(uint4v*)(ylds + (rg * 4 + j) * YSTRIDE + (g & 3) * 64 + q * 8) = st;
      }
    }
    float4v acc[4];
#pragma unroll
    for (int t = 0; t < 4; ++t) acc[t] = (float4v){bias[t], bias[t], bias[t], bias[t]};
#pragma unroll
    for (int s2 = 0; s2 < 8; ++s2) {
      half8 af = *(half8*)(ylds + col * YSTRIDE + s2 * 32 + quad * 8);
      const int sW = s2 & 1;
#pragma unroll
      for (int t = 0; t < 4; ++t)
        acc[t] = __builtin_amdgcn_mfma_f32_16x16x32_f16(af, bfrag[sW][t], acc[t], 0, 0, 0);
    }
#pragma unroll
    for (int t = 0; t < 4; ++t)
#pragma unroll
      for (int reg = 0; reg < 4; ++reg) {
        const int row = row0 + quad * 4 + reg;
        if (row < n) {
          const int j = t * 16 + col;
          if (j < 32)
            out_mu[(size_t)row * 32 + j] = acc[t][reg];
          else
            out_lv[(size_t)row * 32 + (j - 32)] = acc[t][reg];
        }
      }
  }
}

extern "C" void kernel_launch(void* const* d_in, const int* in_sizes, int n_in,
                              void* d_out, int out_size, void* d_ws, size_t ws_size,
                              hipStream_t stream) {
  const float* x = (const float*)d_in[0];
  const int* ei = (const int*)d_in[1];  // [2, E] row-major int32
  const float* W1 = (const float*)d_in[2];
  const float* b1 = (const float*)d_in[3];
  const float* Wmu = (const float*)d_in[4];
  const float* bmu = (const float*)d_in[5];
  const float* Wlv = (const float*)d_in[6];
  const float* blv = (const float*)d_in[7];

  const int N = in_sizes[0] / 64;
  const int E = in_sizes[1] / 2;
  const int* src = ei;
  const int* dst = ei + E;

  const int NBK = (N + BKT_NODES - 1) >> BKT_SHIFT;  // 196 buckets
  const int NSUB = NBK * 8;                          // 1568 sub-regions
  // cap = mean-per-sub + 32 sigma, rounded to 128 (2048 for E=1.6M).
  const int cap = ((E / NSUB + 1024 + 127) / 128) * 128;

  auto align256 = [](size_t v) { return (v + 255) & ~(size_t)255; };
  char* p = (char*)d_ws;
  int* row_ptr = (int*)p;  p += align256((size_t)(N + 1) * 4);
  float* dinv = (float*)p; p += align256((size_t)N * 4);
  int* cursors = (int*)p;  p += align256((size_t)NSUB * 4);
  int* pairs = (int*)p;    p += align256((size_t)E * 4);
  __half* xs = (__half*)p; p += align256((size_t)(N + 1) * 64 * 2);
  size_t tmp_bytes = (size_t)NSUB * cap * 4;  // ~12.85MB
  size_t hs_bytes = (size_t)(N + 1) * 64 * 2;
  int* tmp = (int*)p;      // union: tmp dead after bucket_build; hs written later
  __half* hs = (__half*)p;
  p += align256(tmp_bytes > hs_bytes ? tmp_bytes : hs_bytes);

  float* out_mu = (float*)d_out;
  float* out_lv = out_mu + (size_t)N * 32;

  const int n4 = N * 16;

  // --- CSR build: memset + single edge pass + per-bucket build ---
  hipMemsetAsync(cursors, 0, (size_t)NSUB * 4, stream);
  const int T4 = (E + 3) / 4;
  scatter_direct<<<(T4 + 255) / 256, 256, 0, stream>>>(src, dst, cursors, tmp, E, cap);
  bucket_build<<<NBK, 1024, 0, stream>>>(tmp, cursors, row_ptr, dinv, pairs,
                                         N, NBK, cap, E);

  // --- tables (after bucket_build: hs aliases tmp) ---
  cast_scale<<<(n4 + 32 + 255) / 256, 256, 0, stream>>>(x, dinv, xs, hs, n4, N);

  // --- aggregation + fused dense layers (MFMA epilogue) ---
  const int ntiles = (N + 15) / 16;
  const int ablocks = (ntiles + 3) / 4;  // 1 tile (16 rows) per wave
  agg_layer1<<<ablocks, 256, 0, stream>>>(xs, pairs, row_ptr, W1, b1, hs, N);
  agg_layer2<<<ablocks, 256, 0, stream>>>(hs, pairs, row_ptr, Wmu, bmu, Wlv, blv,
                                          out_mu, out_lv, N);
}